// Round 1
// baseline (4851.402 us; speedup 1.0000x reference)
//
#include <hip/hip_runtime.h>
#include <cmath>

#define BB 2
#define AA 5
#define CH 64
#define HH 128
#define WW 128
#define HW (HH*WW)

// ---------------------------------------------------------------------------
// Kernel 1: fused double-bilinear warp + masked mean over senders j != i.
//   out mean[b,i,c,h,w] = (1/(A-1)) * sum_{j!=i} shift(rot(feats[b,j]))
// Stage-2 (translation) has constant integer shift (sx,sy) + constant 2x2
// bilinear weights => block stages rotation-resampled f on a shifted 17x17
// tile in LDS, then does the 2x2 combine. Accumulate over j in registers.
// grid: x = 64 spatial tiles (16x16), y = 4 channel groups (16ch), z = b*A+i
// ---------------------------------------------------------------------------
__global__ __launch_bounds__(256) void warp_mean_kernel(
    const float* __restrict__ src,    // [B*A, C, H, W]
    const float* __restrict__ trans,  // [B, A, A, 4, 4]
    float* __restrict__ mean)         // [B*A, C, H, W]
{
    __shared__ float f_lds[16][17][18];   // [c][qy][qx], padded inner dim

    const int tile = blockIdx.x;
    const int tx0 = (tile & 7) * 16;
    const int ty0 = (tile >> 3) * 16;
    const int c0  = blockIdx.y * 16;
    const int bi  = blockIdx.z;           // b*A + i
    const int b   = bi / AA, i = bi % AA;
    const int tid = threadIdx.x;
    const int ltx = tid & 15, lty = tid >> 4;

    float acc[16];
#pragma unroll
    for (int c = 0; c < 16; ++c) acc[c] = 0.f;

    for (int j = 0; j < AA; ++j) {
        if (j == i) continue;
        const float* t = trans + (((size_t)b * AA + i) * AA + j) * 16;
        const float t00 = t[0], t01 = t[1], t03 = t[3];
        const float t10 = t[4], t11 = t[5], t13 = t[7];
        // stage-2 pixel shift: x = w + 2*t03, y = h - 2*t13
        const float dx = 2.f * t03;
        const float dy = -2.f * t13;
        const float sxf = floorf(dx), syf = floorf(dy);
        const int sx = (int)sxf, sy = (int)syf;
        const float fx = dx - sxf, fy = dy - syf;
        const float* srcj = src + ((size_t)(b * AA + j) * CH + c0) * HW;

        // ---- stage f over q in [ty0+sy, ty0+sy+16] x [tx0+sx, tx0+sx+16]
        for (int idx = tid; idx < 17 * 17; idx += 256) {
            const int lx = idx % 17, ly = idx / 17;
            const int qx = tx0 + sx + lx;
            const int qy = ty0 + sy + ly;
            const bool qin = (qx >= 0) & (qx < WW) & (qy >= 0) & (qy < HH);
            if (!qin) {
#pragma unroll
                for (int c = 0; c < 16; ++c) f_lds[c][ly][lx] = 0.f;
            } else {
                // normalized coords of pixel center (align_corners=False)
                const float xn = (2 * qx + 1) * (1.0f / WW) - 1.f;
                const float yn = (2 * qy + 1) * (1.0f / HH) - 1.f;
                const float sxn = t00 * xn + t01 * yn;
                const float syn = t10 * xn + t11 * yn;
                const float px = 64.f * sxn + 63.5f;
                const float py = 64.f * syn + 63.5f;
                const float x0f = floorf(px), y0f = floorf(py);
                const int x0 = (int)x0f, y0 = (int)y0f;
                const float wx1 = px - x0f, wx0 = 1.f - wx1;
                const float wy1 = py - y0f, wy0 = 1.f - wy1;
                const bool vx0 = (x0 >= 0) & (x0 < WW);
                const bool vx1 = (x0 + 1 >= 0) & (x0 + 1 < WW);
                const bool vy0 = (y0 >= 0) & (y0 < HH);
                const bool vy1 = (y0 + 1 >= 0) & (y0 + 1 < HH);
                const int cx0 = min(max(x0, 0), WW - 1);
                const int cx1 = min(max(x0 + 1, 0), WW - 1);
                const int cy0 = min(max(y0, 0), HH - 1);
                const int cy1 = min(max(y0 + 1, 0), HH - 1);
                const float w00 = (vx0 & vy0) ? wx0 * wy0 : 0.f;
                const float w01 = (vx1 & vy0) ? wx1 * wy0 : 0.f;
                const float w10 = (vx0 & vy1) ? wx0 * wy1 : 0.f;
                const float w11 = (vx1 & vy1) ? wx1 * wy1 : 0.f;
                const int o00 = cy0 * WW + cx0, o01 = cy0 * WW + cx1;
                const int o10 = cy1 * WW + cx0, o11 = cy1 * WW + cx1;
#pragma unroll
                for (int c = 0; c < 16; ++c) {
                    const float* p = srcj + c * HW;
                    f_lds[c][ly][lx] = w00 * p[o00] + w01 * p[o01]
                                     + w10 * p[o10] + w11 * p[o11];
                }
            }
        }
        __syncthreads();

        // ---- stage 2: constant 2x2 combine
        const float wA = (1.f - fx) * (1.f - fy);
        const float wB = fx * (1.f - fy);
        const float wC = (1.f - fx) * fy;
        const float wD = fx * fy;
#pragma unroll
        for (int c = 0; c < 16; ++c) {
            const float v00 = f_lds[c][lty][ltx];
            const float v01 = f_lds[c][lty][ltx + 1];
            const float v10 = f_lds[c][lty + 1][ltx];
            const float v11 = f_lds[c][lty + 1][ltx + 1];
            acc[c] += wA * v00 + wB * v01 + wC * v10 + wD * v11;
        }
        __syncthreads();
    }

    float* dst = mean + ((size_t)bi * CH + c0) * HW + (ty0 + lty) * WW + (tx0 + ltx);
    const float inv = 1.f / (AA - 1);
#pragma unroll
    for (int c = 0; c < 16; ++c) dst[c * HW] = acc[c] * inv;
}

// ---------------------------------------------------------------------------
// Kernel 2: 3x3 SAME conv (in = concat(feats, mean) = 128ch, out = 192ch)
// fused with ConvGRU step (h0=0): out = (1-sigmoid(xz+bz)) * tanh(xn + r*bn),
// r = sigmoid(xr+br). Each thread: 1 pixel x 16 out-ch x 3 gates = 48 accs.
// Weights are block-uniform -> scalar loads (SGPR broadcast).
// grid: x = 64 tiles, y = 4 out-channel groups, z = image (b*A+a)
// ---------------------------------------------------------------------------
__global__ __launch_bounds__(256) void conv_gru_kernel(
    const float* __restrict__ src,    // [B*A, 64, H, W]
    const float* __restrict__ mean,   // [B*A, 64, H, W]
    const float* __restrict__ wx,     // [192, 128, 3, 3]
    const float* __restrict__ bx,     // [192]
    const float* __restrict__ bh,     // [192]
    float* __restrict__ dst)          // [B*A, 64, H, W]
{
    __shared__ float in_lds[16][18][19];  // [ci][y][x] with halo, padded

    const int tile = blockIdx.x;
    const int tx0 = (tile & 7) * 16;
    const int ty0 = (tile >> 3) * 16;
    const int c0  = blockIdx.y * 16;
    const int img = blockIdx.z;
    const int tid = threadIdx.x;
    const int ltx = tid & 15, lty = tid >> 4;

    float acc[48];
#pragma unroll
    for (int k = 0; k < 48; ++k) acc[k] = 0.f;

    for (int chunk = 0; chunk < 8; ++chunk) {
        const int ci0 = chunk * 16;
        const float* X = (ci0 < 64)
            ? (src  + ((size_t)img * CH + ci0) * HW)
            : (mean + ((size_t)img * CH + (ci0 - 64)) * HW);

        __syncthreads();
        for (int idx = tid; idx < 18 * 18; idx += 256) {
            const int xx = idx % 18, yy = idx / 18;
            const int gx = tx0 + xx - 1, gy = ty0 + yy - 1;
            const bool in = (gx >= 0) & (gx < WW) & (gy >= 0) & (gy < HH);
            const int off = in ? gy * WW + gx : 0;
#pragma unroll
            for (int c = 0; c < 16; ++c)
                in_lds[c][yy][xx] = in ? X[c * HW + off] : 0.f;
        }
        __syncthreads();

        for (int c = 0; c < 16; ++c) {
            float v[9];
#pragma unroll
            for (int ky = 0; ky < 3; ++ky)
#pragma unroll
                for (int kx = 0; kx < 3; ++kx)
                    v[ky * 3 + kx] = in_lds[c][lty + ky][ltx + kx];
            const int ci = ci0 + c;
#pragma unroll
            for (int g = 0; g < 3; ++g) {
#pragma unroll
                for (int cc = 0; cc < 16; ++cc) {
                    const float* wp = wx + ((size_t)(g * 64 + c0 + cc) * 128 + ci) * 9;
                    float a = acc[g * 16 + cc];
#pragma unroll
                    for (int tp = 0; tp < 9; ++tp) a = fmaf(v[tp], wp[tp], a);
                    acc[g * 16 + cc] = a;
                }
            }
        }
    }

    // epilogue: GRU gating (h0 = 0)
    const int gy = ty0 + lty, gx = tx0 + ltx;
#pragma unroll
    for (int cc = 0; cc < 16; ++cc) {
        const int c = c0 + cc;
        const float xr = acc[cc]      + bx[c]       + bh[c];
        const float xz = acc[16 + cc] + bx[64 + c]  + bh[64 + c];
        const float xn = acc[32 + cc] + bx[128 + c];
        const float r = 1.f / (1.f + __expf(-xr));
        const float z = 1.f / (1.f + __expf(-xz));
        const float n = tanhf(xn + r * bh[128 + c]);
        dst[((size_t)img * CH + c) * HW + gy * WW + gx] = (1.f - z) * n;
    }
}

// ---------------------------------------------------------------------------
extern "C" void kernel_launch(void* const* d_in, const int* in_sizes, int n_in,
                              void* d_out, int out_size, void* d_ws, size_t ws_size,
                              hipStream_t stream) {
    const float* feats = (const float*)d_in[0];
    const float* trans = (const float*)d_in[1];
    const float* wx    = (const float*)d_in[2];
    // d_in[3] = wh  (unused: h0 = 0 so hidden convs vanish, only bh remains)
    const float* bx    = (const float*)d_in[4];
    const float* bh    = (const float*)d_in[5];
    float* out = (float*)d_out;

    const size_t feat_elems = (size_t)BB * AA * CH * HW;   // 10,485,760
    float* mean = (float*)d_ws;                 // [B*A, C, H, W]
    float* ftmp = (float*)d_ws + feat_elems;    // [B*A, C, H, W]

    dim3 grid(64, 4, BB * AA);
    dim3 block(256);

    // iteration 1: feats(in) -> ftmp
    warp_mean_kernel<<<grid, block, 0, stream>>>(feats, trans, mean);
    conv_gru_kernel<<<grid, block, 0, stream>>>(feats, mean, wx, bx, bh, ftmp);
    // iteration 2: ftmp -> out
    warp_mean_kernel<<<grid, block, 0, stream>>>(ftmp, trans, mean);
    conv_gru_kernel<<<grid, block, 0, stream>>>(ftmp, mean, wx, bx, bh, out);
}

// Round 2
// 438.461 us; speedup vs baseline: 11.0646x; 11.0646x over previous
//
#include <hip/hip_runtime.h>
#include <cmath>

#define BB 2
#define AA 5
#define CH 64
#define HH 128
#define WW 128
#define HW (HH*WW)
#define NIMG (BB*AA)

typedef __attribute__((ext_vector_type(8))) _Float16 half8;
typedef __attribute__((ext_vector_type(4))) float floatx4;

__device__ inline half8 hzero() {
    half8 v;
#pragma unroll
    for (int e = 0; e < 8; ++e) v[e] = (_Float16)0.f;
    return v;
}

// ---------------------------------------------------------------------------
// feats fp32 planar [NIMG,64,H,W] -> NHWC f16 buffer channels 0..63
// ---------------------------------------------------------------------------
__global__ __launch_bounds__(256) void to_nhwc_kernel(
    const float* __restrict__ src, _Float16* __restrict__ dst)
{
    const int img = blockIdx.y;
    const int cg  = blockIdx.x & 7;       // 8 groups of 8 channels
    const int pb  = blockIdx.x >> 3;      // 64 pixel blocks of 256
    const int p   = pb * 256 + threadIdx.x;
    const float* s = src + ((size_t)img * CH + cg * 8) * HW + p;
    half8 v;
#pragma unroll
    for (int e = 0; e < 8; ++e) v[e] = (_Float16)s[e * HW];
    *(half8*)(dst + ((size_t)img * HW + p) * 128 + cg * 8) = v;
}

// ---------------------------------------------------------------------------
// pack wx [192,128,3,3] fp32 -> f16 B-fragment layout:
// wp[cc][tap][gk][oc][e] : k = cc*32 + gk*8 + e, tap = ky*3+kx
// ---------------------------------------------------------------------------
__global__ __launch_bounds__(256) void pack_w_kernel(
    const float* __restrict__ wx, half8* __restrict__ wp)
{
    int idx = blockIdx.x * 256 + threadIdx.x;     // 4*9*4*192 = 27648
    if (idx >= 4 * 9 * 4 * 192) return;
    int oc = idx % 192; int r = idx / 192;
    int gk = r & 3; r >>= 2; int tap = r % 9; int cc = r / 9;
    int ky = tap / 3, kx = tap % 3;
    half8 v;
#pragma unroll
    for (int e = 0; e < 8; ++e)
        v[e] = (_Float16)wx[(((size_t)oc * 128 + cc * 32 + gk * 8 + e) * 3 + ky) * 3 + kx];
    wp[idx] = v;
}

// ---------------------------------------------------------------------------
// fused double-bilinear warp + masked mean; NHWC f16 in (ch 0..63),
// NHWC f16 out (ch 64..127 of the SAME buffer).
// grid: x = 64 tiles (16x16 px), y = 4 ch-groups (16ch), z = b*A+i
// ---------------------------------------------------------------------------
__global__ __launch_bounds__(256) void warp_mean_kernel(
    const _Float16* __restrict__ nh,     // [NIMG, HW, 128]
    const float* __restrict__ trans,     // [B, A, A, 4, 4]
    _Float16* __restrict__ nhw)          // same buffer
{
    __shared__ float f_lds[16][17][18];

    const int tile = blockIdx.x;
    const int tx0 = (tile & 7) * 16;
    const int ty0 = (tile >> 3) * 16;
    const int c0  = blockIdx.y * 16;
    const int bi  = blockIdx.z;
    const int b   = bi / AA, i = bi % AA;
    const int tid = threadIdx.x;
    const int ltx = tid & 15, lty = tid >> 4;

    float acc[16];
#pragma unroll
    for (int c = 0; c < 16; ++c) acc[c] = 0.f;

    for (int j = 0; j < AA; ++j) {
        if (j == i) continue;
        const float* t = trans + (((size_t)b * AA + i) * AA + j) * 16;
        const float t00 = t[0], t01 = t[1], t03 = t[3];
        const float t10 = t[4], t11 = t[5], t13 = t[7];
        const float dxs = 2.f * t03;
        const float dys = -2.f * t13;
        const float sxf = floorf(dxs), syf = floorf(dys);
        const int sx = (int)sxf, sy = (int)syf;
        const float fx = dxs - sxf, fy = dys - syf;
        const _Float16* srcj = nh + (size_t)(b * AA + j) * HW * 128 + c0;

        for (int idx = tid; idx < 17 * 17; idx += 256) {
            const int lx = idx % 17, ly = idx / 17;
            const int qx = tx0 + sx + lx;
            const int qy = ty0 + sy + ly;
            const bool qin = (qx >= 0) & (qx < WW) & (qy >= 0) & (qy < HH);
            if (!qin) {
#pragma unroll
                for (int c = 0; c < 16; ++c) f_lds[c][ly][lx] = 0.f;
            } else {
                const float xn = (2 * qx + 1) * (1.0f / WW) - 1.f;
                const float yn = (2 * qy + 1) * (1.0f / HH) - 1.f;
                const float sxn = t00 * xn + t01 * yn;
                const float syn = t10 * xn + t11 * yn;
                const float px = 64.f * sxn + 63.5f;
                const float py = 64.f * syn + 63.5f;
                const float x0f = floorf(px), y0f = floorf(py);
                const int x0 = (int)x0f, y0 = (int)y0f;
                const float wx1 = px - x0f, wx0 = 1.f - wx1;
                const float wy1 = py - y0f, wy0 = 1.f - wy1;
                const bool vx0 = (x0 >= 0) & (x0 < WW);
                const bool vx1 = (x0 + 1 >= 0) & (x0 + 1 < WW);
                const bool vy0 = (y0 >= 0) & (y0 < HH);
                const bool vy1 = (y0 + 1 >= 0) & (y0 + 1 < HH);
                const int cx0 = min(max(x0, 0), WW - 1);
                const int cx1 = min(max(x0 + 1, 0), WW - 1);
                const int cy0 = min(max(y0, 0), HH - 1);
                const int cy1 = min(max(y0 + 1, 0), HH - 1);
                const float w00 = (vx0 & vy0) ? wx0 * wy0 : 0.f;
                const float w01 = (vx1 & vy0) ? wx1 * wy0 : 0.f;
                const float w10 = (vx0 & vy1) ? wx0 * wy1 : 0.f;
                const float w11 = (vx1 & vy1) ? wx1 * wy1 : 0.f;
                const size_t o00 = ((size_t)cy0 * WW + cx0) * 128;
                const size_t o01 = ((size_t)cy0 * WW + cx1) * 128;
                const size_t o10 = ((size_t)cy1 * WW + cx0) * 128;
                const size_t o11 = ((size_t)cy1 * WW + cx1) * 128;
                const half8 a0 = *(const half8*)(srcj + o00);
                const half8 a1 = *(const half8*)(srcj + o00 + 8);
                const half8 b0 = *(const half8*)(srcj + o01);
                const half8 b1 = *(const half8*)(srcj + o01 + 8);
                const half8 c0v = *(const half8*)(srcj + o10);
                const half8 c1v = *(const half8*)(srcj + o10 + 8);
                const half8 d0 = *(const half8*)(srcj + o11);
                const half8 d1 = *(const half8*)(srcj + o11 + 8);
#pragma unroll
                for (int c = 0; c < 16; ++c) {
                    const float p00 = (c < 8) ? (float)a0[c & 7] : (float)a1[c & 7];
                    const float p01 = (c < 8) ? (float)b0[c & 7] : (float)b1[c & 7];
                    const float p10 = (c < 8) ? (float)c0v[c & 7] : (float)c1v[c & 7];
                    const float p11 = (c < 8) ? (float)d0[c & 7] : (float)d1[c & 7];
                    f_lds[c][ly][lx] = w00 * p00 + w01 * p01 + w10 * p10 + w11 * p11;
                }
            }
        }
        __syncthreads();

        const float wA = (1.f - fx) * (1.f - fy);
        const float wB = fx * (1.f - fy);
        const float wC = (1.f - fx) * fy;
        const float wD = fx * fy;
#pragma unroll
        for (int c = 0; c < 16; ++c) {
            const float v00 = f_lds[c][lty][ltx];
            const float v01 = f_lds[c][lty][ltx + 1];
            const float v10 = f_lds[c][lty + 1][ltx];
            const float v11 = f_lds[c][lty + 1][ltx + 1];
            acc[c] += wA * v00 + wB * v01 + wC * v10 + wD * v11;
        }
        __syncthreads();
    }

    const float inv = 1.f / (AA - 1);
    _Float16* dst = nhw + ((size_t)bi * HW + (ty0 + lty) * WW + tx0 + ltx) * 128 + 64 + c0;
    half8 o0, o1;
#pragma unroll
    for (int c = 0; c < 8; ++c) { o0[c] = (_Float16)(acc[c] * inv); o1[c] = (_Float16)(acc[c + 8] * inv); }
    *(half8*)dst = o0;
    *(half8*)(dst + 8) = o1;
}

// ---------------------------------------------------------------------------
// MFMA implicit-GEMM 3x3 conv (128ch NHWC f16 in, 192 oc) + fused GRU gating.
// Block: 128 px (16x8) x 192 oc, 4 waves, each wave 64 px x 96 oc (24 frags).
// K-loop: 4 ci-chunks x 9 taps, 16x16x32 f16 MFMA.
// Output: fp32 planar (final) OR f16 NHWC ch0..63 (intermediate).
// ---------------------------------------------------------------------------
__global__ __launch_bounds__(256) void conv_gru_mfma(
    const _Float16* __restrict__ in,    // [NIMG, HW, 128]
    const half8* __restrict__ wp,       // packed weights
    const float* __restrict__ bx,       // [192]
    const float* __restrict__ bh,       // [192]
    float* __restrict__ out_f32,        // [NIMG,64,H,W] or null
    _Float16* __restrict__ out_f16)     // [NIMG,HW,128] ch0..63 or null
{
    __shared__ half8 lds_in[720];   // [g=4][py=10][px=18]  (ci-chunk of 32)
    __shared__ half8 lds_B[768];    // [gk=4][oc=192]

    const int tid = threadIdx.x;
    const int img = blockIdx.z;
    const int x0 = (blockIdx.x & 7) * 16;
    const int y0 = (blockIdx.x >> 3) * 8;
    const int w   = tid >> 6;
    const int ln  = tid & 15;
    const int kq  = (tid & 63) >> 4;
    const int och = w & 1, pxh = w >> 1;

    floatx4 acc[4][6];
#pragma unroll
    for (int s = 0; s < 4; ++s)
#pragma unroll
        for (int t = 0; t < 6; ++t)
#pragma unroll
            for (int r = 0; r < 4; ++r) acc[s][t][r] = 0.f;

    const _Float16* inimg = in + (size_t)img * HW * 128;

    for (int cc = 0; cc < 4; ++cc) {
        __syncthreads();   // prior-iteration lds_in reads complete
        for (int f = tid; f < 720; f += 256) {
            const int g = f / 180; const int r = f % 180;
            const int py = r / 18; const int px = r % 18;
            const int y = y0 + py - 1, x = x0 + px - 1;
            half8 v = hzero();
            if ((unsigned)x < (unsigned)WW && (unsigned)y < (unsigned)HH)
                v = *(const half8*)(inimg + ((size_t)y * WW + x) * 128 + cc * 32 + g * 8);
            lds_in[f] = v;
        }
        for (int tap = 0; tap < 9; ++tap) {
            __syncthreads();   // prior B reads complete (and input staged, tap 0)
            const half8* wsrc = wp + (cc * 9 + tap) * 768;
            lds_B[tid]       = wsrc[tid];
            lds_B[tid + 256] = wsrc[tid + 256];
            lds_B[tid + 512] = wsrc[tid + 512];
            __syncthreads();   // B ready
            const int dy = tap / 3, dx = tap % 3;
            half8 a[4], b[6];
#pragma unroll
            for (int s = 0; s < 4; ++s)
                a[s] = lds_in[(kq * 10 + pxh * 4 + s + dy) * 18 + ln + dx];
#pragma unroll
            for (int t = 0; t < 6; ++t)
                b[t] = lds_B[kq * 192 + (t >> 1) * 64 + och * 32 + (t & 1) * 16 + ln];
#pragma unroll
            for (int s = 0; s < 4; ++s)
#pragma unroll
                for (int t = 0; t < 6; ++t)
                    acc[s][t] = __builtin_amdgcn_mfma_f32_16x16x32_f16(a[s], b[t], acc[s][t], 0, 0, 0);
        }
    }

    // epilogue: GRU gating. D layout: col(oc) = ln, row(x) = kq*4+reg.
#pragma unroll
    for (int cp = 0; cp < 2; ++cp) {
        const int c = och * 32 + cp * 16 + ln;          // 0..63
        const float bxr = bx[c] + bh[c];
        const float bxz = bx[64 + c] + bh[64 + c];
        const float bxn = bx[128 + c];
        const float bnn = bh[128 + c];
#pragma unroll
        for (int s = 0; s < 4; ++s) {
            const int y = y0 + pxh * 4 + s;
#pragma unroll
            for (int reg = 0; reg < 4; ++reg) {
                const int x = x0 + kq * 4 + reg;
                const float xr = acc[s][cp][reg] + bxr;
                const float xz = acc[s][2 + cp][reg] + bxz;
                const float xn = acc[s][4 + cp][reg] + bxn;
                const float rg = 1.f / (1.f + __expf(-xr));
                const float zg = 1.f / (1.f + __expf(-xz));
                const float n  = tanhf(xn + rg * bnn);
                const float h  = (1.f - zg) * n;
                if (out_f32)
                    out_f32[((size_t)img * CH + c) * HW + y * WW + x] = h;
                else
                    out_f16[((size_t)img * HW + y * WW + x) * 128 + c] = (_Float16)h;
            }
        }
    }
}

// ---------------------------------------------------------------------------
extern "C" void kernel_launch(void* const* d_in, const int* in_sizes, int n_in,
                              void* d_out, int out_size, void* d_ws, size_t ws_size,
                              hipStream_t stream) {
    const float* feats = (const float*)d_in[0];
    const float* trans = (const float*)d_in[1];
    const float* wx    = (const float*)d_in[2];
    // d_in[3] = wh (unused: h0 = 0)
    const float* bx    = (const float*)d_in[4];
    const float* bh    = (const float*)d_in[5];
    float* out = (float*)d_out;

    char* ws = (char*)d_ws;
    half8*    wpack = (half8*)ws;                              // 442,368 B
    _Float16* B1 = (_Float16*)(ws + 442368);                   // 40 MB NHWC f16
    _Float16* B2 = (_Float16*)(ws + 442368 + (size_t)NIMG * HW * 128 * 2);

    pack_w_kernel<<<108, 256, 0, stream>>>(wx, wpack);
    to_nhwc_kernel<<<dim3(512, NIMG), 256, 0, stream>>>(feats, B1);

    dim3 wgrid(64, 4, NIMG);
    dim3 cgrid(128, 1, NIMG);

    // iteration 1
    warp_mean_kernel<<<wgrid, 256, 0, stream>>>(B1, trans, B1);
    conv_gru_mfma<<<cgrid, 256, 0, stream>>>(B1, wpack, bx, bh, nullptr, B2);
    // iteration 2
    warp_mean_kernel<<<wgrid, 256, 0, stream>>>(B2, trans, B2);
    conv_gru_mfma<<<cgrid, 256, 0, stream>>>(B2, wpack, bx, bh, out, nullptr);
}